// Round 3
// baseline (263.526 us; speedup 1.0000x reference)
//
#include <hip/hip_runtime.h>
#include <math.h>

#define TOK 16384
#define DD  2048
#define EE  64
#define MT  32           // tokens per block
#define KCW 32           // K-chunks (of 32) per wave; kw splits K=2048 in halves

typedef _Float16 half8  __attribute__((ext_vector_type(8)));
typedef float    floatx4 __attribute__((ext_vector_type(4)));

// ---- W pre-split: f32 -> (hi,lo) f16, wave-grouped frag layout ----
// frag id = kc*16 + cw4*4 + nf*2 + s   (kc 0..63 global, cw4 = ct&3, nf = ct>>2)
// half8 index = fragid*64 + lane. So one wave's 4 frags per chunk are contiguous
// (offsets 0..3 KiB from a single base).
__global__ void build_wf(const float* __restrict__ Wg, const float* __restrict__ Wn,
                         _Float16* __restrict__ wf) {
  int tid  = blockIdx.x * 256 + threadIdx.x;   // 32768 threads
  int lane = tid & 63;
  int kc   = (tid >> 6) & 63;
  int ct   = tid >> 12;                        // 0..7
  int col  = (ct & 3) * 16 + (lane & 15);
  int k    = kc * 32 + (lane >> 4) * 8;
  const float* W = (ct < 4) ? Wg : Wn;
  const float* src = W + (size_t)col * DD + k;
  float4 a = *reinterpret_cast<const float4*>(src);
  float4 b = *reinterpret_cast<const float4*>(src + 4);
  float v[8] = {a.x, a.y, a.z, a.w, b.x, b.y, b.z, b.w};
  half8 hi, lo;
#pragma unroll
  for (int j = 0; j < 8; ++j) {
    _Float16 h = (_Float16)v[j];
    hi[j] = h;
    lo[j] = (_Float16)(v[j] - (float)h);
  }
  int cw4 = ct & 3;
  int nf  = ct >> 2;
  size_t base = (((size_t)(kc * 16 + cw4 * 4 + nf * 2) ) * 64 + lane) * 8;
  *reinterpret_cast<half8*>(wf + base)       = hi;   // s=0
  *reinterpret_cast<half8*>(wf + base + 512) = lo;   // s=1 (next frag id)
}

// One K-loop body. CUR/NXT compile-time (rule #20). AOFFE = float offset of the
// A-prefetch chunk relative to xq; BOFFH8 = half8 offset of the B-prefetch chunk
// relative to wq. MFMA order (hihi, hilo, lohi) matches the passing kernel.
#define KBODY(CUR, NXT, AOFFE, BOFFH8, DOA, DOB)                                   \
  {                                                                               \
    half8 Ah[2], Al[2];                                                           \
    _Pragma("unroll")                                                             \
    for (int mt = 0; mt < 2; ++mt) {                                              \
      float v[8] = {Aa[CUR][mt].x, Aa[CUR][mt].y, Aa[CUR][mt].z, Aa[CUR][mt].w,   \
                    Ab[CUR][mt].x, Ab[CUR][mt].y, Ab[CUR][mt].z, Ab[CUR][mt].w};  \
      _Pragma("unroll")                                                           \
      for (int j = 0; j < 8; ++j) {                                               \
        _Float16 h = (_Float16)v[j];                                              \
        Ah[mt][j] = h;                                                            \
        Al[mt][j] = (_Float16)(v[j] - (float)h);                                  \
      }                                                                           \
    }                                                                             \
    if (DOA) {                                                                    \
      Aa[CUR][0] = *reinterpret_cast<const float4*>(xq0 + (AOFFE));               \
      Ab[CUR][0] = *reinterpret_cast<const float4*>(xq0 + (AOFFE) + 4);           \
      Aa[CUR][1] = *reinterpret_cast<const float4*>(xq1 + (AOFFE));               \
      Ab[CUR][1] = *reinterpret_cast<const float4*>(xq1 + (AOFFE) + 4);           \
    }                                                                             \
    if (DOB) {                                                                    \
      _Pragma("unroll")                                                           \
      for (int f = 0; f < 4; ++f) Bf[NXT][f] = wq[(BOFFH8) + f * 64];             \
    }                                                                             \
    _Pragma("unroll")                                                             \
    for (int mt = 0; mt < 2; ++mt)                                                \
      _Pragma("unroll")                                                           \
      for (int nf = 0; nf < 2; ++nf)                                              \
        acc[mt][nf] = __builtin_amdgcn_mfma_f32_16x16x32_f16(                     \
            Ah[mt], Bf[CUR][nf * 2 + 0], acc[mt][nf], 0, 0, 0);                   \
    _Pragma("unroll")                                                             \
    for (int mt = 0; mt < 2; ++mt)                                                \
      _Pragma("unroll")                                                           \
      for (int nf = 0; nf < 2; ++nf)                                              \
        acc[mt][nf] = __builtin_amdgcn_mfma_f32_16x16x32_f16(                     \
            Ah[mt], Bf[CUR][nf * 2 + 1], acc[mt][nf], 0, 0, 0);                   \
    _Pragma("unroll")                                                             \
    for (int mt = 0; mt < 2; ++mt)                                                \
      _Pragma("unroll")                                                           \
      for (int nf = 0; nf < 2; ++nf)                                              \
        acc[mt][nf] = __builtin_amdgcn_mfma_f32_16x16x32_f16(                     \
            Al[mt], Bf[CUR][nf * 2 + 0], acc[mt][nf], 0, 0, 0);                   \
  }

// Barrier-free main loop, 8 waves/block: wave (cw4 = w&3, kw = w>>2) owns
// gate cols [cw4*16,+16) + noise same cols, K-half kw, both 16-token tiles.
// 4096 waves total = 4 waves/SIMD; VGPR capped at 128 for 2 blocks/CU.
__global__ __launch_bounds__(512, 4)
void gating_kernel(const float* __restrict__ x, const float* __restrict__ rn,
                   const _Float16* __restrict__ wf, const float* __restrict__ bg,
                   float* __restrict__ out,
                   float* __restrict__ cnt_g, float* __restrict__ psum_g) {
  __shared__ float Pacc[4096];      // 16 KiB: kw=1 partials, 4 cw4-groups
  __shared__ float Vb[MT * 65];     // noisy logits
  __shared__ float Eb[MT * 65];     // exp(noisy)
  __shared__ float isum[MT];
  __shared__ int   ti[MT * 2];
  __shared__ float tp[MT * 2];

  const int t   = threadIdx.x;
  const int w   = t >> 6;
  const int cw4 = w & 3;        // column tile: cols [cw4*16, +16)
  const int kw  = w >> 2;       // K-half
  const int l   = t & 63;
  const int q   = l >> 4;
  const int cl  = l & 15;
  const int t0  = blockIdx.x * MT;

  // A-frag native addresses: lane covers token row cl, k = q*8..q*8+7
  const float* xb0 = x + (size_t)(t0 + cl) * DD + kw * (KCW * 32) + q * 8;
  const float* xb1 = xb0 + (size_t)16 * DD;

  // B-frag base for (kw, cw4) in half8 units
  const half8* wb = reinterpret_cast<const half8*>(wf)
                  + (size_t)kw * (KCW * 1024) + cw4 * 256 + l;

  floatx4 acc[2][2];            // [token-tile][0=gate,1=noise]
#pragma unroll
  for (int mt = 0; mt < 2; ++mt)
#pragma unroll
    for (int nf = 0; nf < 2; ++nf) acc[mt][nf] = (floatx4)0.f;

  float4 Aa[2][2], Ab[2][2];    // [buf][mt] : A f32, 2 chunks deep
  half8  Bf[2][4];              // [buf][nf*2+s] : B frags, 1 chunk deep

  // preamble: A chunks 0,1 ; B chunk 0
#pragma unroll
  for (int mt = 0; mt < 2; ++mt) {
    const float* xb = (mt == 0) ? xb0 : xb1;
    Aa[0][mt] = *reinterpret_cast<const float4*>(xb);
    Ab[0][mt] = *reinterpret_cast<const float4*>(xb + 4);
    Aa[1][mt] = *reinterpret_cast<const float4*>(xb + 32);
    Ab[1][mt] = *reinterpret_cast<const float4*>(xb + 36);
  }
#pragma unroll
  for (int f = 0; f < 4; ++f) Bf[0][f] = wb[f * 64];

  // running prefetch pointers: xq -> chunk kc+2, wq -> chunk kc+1
  const float* xq0 = xb0 + 64;
  const float* xq1 = xb1 + 64;
  const half8* wq  = wb + 1024;

  for (int it = 0; it < (KCW - 2) / 2; ++it) {   // bodies 0..29
    KBODY(0, 1, 0, 0, 1, 1)
    KBODY(1, 0, 32, 1024, 1, 1)
    xq0 += 64; xq1 += 64; wq += 2048;
  }
  KBODY(0, 1, 0, 0, 0, 1)      // body 30: prefetch B(31) only
  KBODY(1, 0, 0, 0, 0, 0)      // body 31: consume only

  // epilogue operand preload (overlaps merge)
  float bgv = 0.f;
  float rnv[2][4];
  if (kw == 0) {
    bgv = bg[cw4 * 16 + cl];
#pragma unroll
    for (int mt = 0; mt < 2; ++mt)
#pragma unroll
      for (int r = 0; r < 4; ++r)
        rnv[mt][r] = rn[(size_t)(t0 + mt * 16 + q * 4 + r) * EE + cw4 * 16 + cl];
  }

  // ---- split-K merge: kw=1 -> LDS, kw=0 adds ----
  if (kw == 1) {
#pragma unroll
    for (int mt = 0; mt < 2; ++mt)
#pragma unroll
      for (int nf = 0; nf < 2; ++nf)
#pragma unroll
        for (int r = 0; r < 4; ++r)
          Pacc[(cw4 * 16 + (mt * 2 + nf) * 4 + r) * 64 + l] = acc[mt][nf][r];
  }
  __syncthreads();

  if (kw == 0) {
#pragma unroll
    for (int mt = 0; mt < 2; ++mt)
#pragma unroll
      for (int nf = 0; nf < 2; ++nf)
#pragma unroll
        for (int r = 0; r < 4; ++r)
          acc[mt][nf][r] += Pacc[(cw4 * 16 + (mt * 2 + nf) * 4 + r) * 64 + l];

    // noisy logit + exp, in-register (gate nf=0 / noise nf=1 in same lane)
#pragma unroll
    for (int mt = 0; mt < 2; ++mt)
#pragma unroll
      for (int r = 0; r < 4; ++r) {
        const int tk = mt * 16 + q * 4 + r;   // C/D layout: row = q*4+r
        const int c  = cw4 * 16 + cl;
        float gt = acc[mt][0][r] + bgv;
        float h  = acc[mt][1][r];
        float sp = (h > 20.f) ? h : log1pf(expf(h));
        float v  = gt + rnv[mt][r] * (sp + 0.01f);
        Vb[tk * 65 + c] = v;
        Eb[tk * 65 + c] = expf(v);
      }
  }
  __syncthreads();

  // ---- per-token top-2 + softmax denom (32 threads) ----
  if (t < MT) {
    float v1 = -1e30f, v2 = -1e30f;
    int   i1 = 0, i2 = 0;
    float s = 0.f;
    for (int e = 0; e < EE; ++e) {
      float v = Vb[t * 65 + e];
      s += Eb[t * 65 + e];
      if (v > v1)      { v2 = v1; i2 = i1; v1 = v; i1 = e; }
      else if (v > v2) { v2 = v;  i2 = e; }
    }
    isum[t] = 1.f / s;
    ti[t * 2 + 0] = i1; ti[t * 2 + 1] = i2;
    float e2 = expf(v2 - v1);
    float dn = 1.f + e2;
    tp[t * 2 + 0] = 1.f / dn;
    tp[t * 2 + 1] = e2 / dn;
  }
  __syncthreads();

  // ---- sparse out: patched zero-fill, 512 threads x one float4 ----
  {
    const int m  = t >> 4;
    const int c0 = (t & 15) * 4;
    const int i1 = ti[m * 2 + 0], i2 = ti[m * 2 + 1];
    const float p1 = tp[m * 2 + 0], p2 = tp[m * 2 + 1];
    float o[4];
#pragma unroll
    for (int j = 0; j < 4; ++j) {
      const int col = c0 + j;
      o[j] = (col == i1) ? p1 : ((col == i2) ? p2 : 0.f);
    }
    *reinterpret_cast<float4*>(out + (size_t)(t0 + m) * EE + c0) =
        make_float4(o[0], o[1], o[2], o[3]);
  }

  // ---- aux partials: per-expert psum & count ----
  if (t < EE) {
    float s = 0.f;
    int   cn = 0;
#pragma unroll
    for (int m = 0; m < MT; ++m) {
      s  += Eb[m * 65 + t] * isum[m];
      cn += (ti[m * 2 + 0] == t) + (ti[m * 2 + 1] == t);
    }
    atomicAdd(&psum_g[t], s);
    atomicAdd(&cnt_g[t], (float)cn);
  }
}

__global__ void aux_kernel(const float* __restrict__ cnt_g,
                           const float* __restrict__ psum_g,
                           float* __restrict__ out) {
  int e = threadIdx.x;  // 64 lanes, one wave
  float v = cnt_g[e] * psum_g[e];
#pragma unroll
  for (int o = 32; o > 0; o >>= 1) v += __shfl_down(v, o);
  if (e == 0)
    out[(size_t)TOK * EE] = v * ((float)EE / ((float)TOK * (float)TOK));
}

extern "C" void kernel_launch(void* const* d_in, const int* in_sizes, int n_in,
                              void* d_out, int out_size, void* d_ws, size_t ws_size,
                              hipStream_t stream) {
  const float* x  = (const float*)d_in[0];
  const float* rn = (const float*)d_in[1];
  const float* Wg = (const float*)d_in[2];
  const float* bg = (const float*)d_in[3];
  const float* Wn = (const float*)d_in[4];
  float* out    = (float*)d_out;
  float* cnt_g  = (float*)d_ws;
  float* psum_g = cnt_g + EE;
  _Float16* wf  = (_Float16*)((float*)d_ws + 128);   // 1 MiB of pre-split W frags

  hipMemsetAsync(d_ws, 0, 2 * EE * sizeof(float), stream);
  build_wf<<<128, 256, 0, stream>>>(Wg, Wn, wf);
  gating_kernel<<<TOK / MT, 512, 0, stream>>>(x, rn, wf, bg, out, cnt_g, psum_g);
  aux_kernel<<<1, 64, 0, stream>>>(cnt_g, psum_g, out);
}

// Round 5
// 237.494 us; speedup vs baseline: 1.1096x; 1.1096x over previous
//
#include <hip/hip_runtime.h>
#include <math.h>

#define TOK 16384
#define DD  2048
#define EE  64
#define MT  32           // tokens per block
#define BK  32           // k per chunk
#define NKC 32           // chunks per K-group (each group covers 1024)
#define LDA 40           // halves per token row in LDS (80B stride, <=2-way conflicts)

typedef _Float16 half4v __attribute__((ext_vector_type(4)));
typedef _Float16 half8  __attribute__((ext_vector_type(8)));
typedef float    floatx4 __attribute__((ext_vector_type(4)));

// ---- W pre-split: f32 -> (hi,lo) f16, frag-major layout ----
// wf frag index ((ct*64+kc)*2+s)*64+lane, 8 halves each.
// ct 0..3 = gate col-tiles (cols ct*16+cl), ct 4..7 = noise col-tiles.
__global__ void build_wf(const float* __restrict__ Wg, const float* __restrict__ Wn,
                         _Float16* __restrict__ wf) {
  int tid  = blockIdx.x * 256 + threadIdx.x;   // 32768 threads
  int lane = tid & 63;
  int kc   = (tid >> 6) & 63;
  int ct   = tid >> 12;                        // 0..7
  int col  = (ct & 3) * 16 + (lane & 15);
  int k    = kc * 32 + (lane >> 4) * 8;
  const float* W = (ct < 4) ? Wg : Wn;
  const float* src = W + (size_t)col * DD + k;
  float4 a = *reinterpret_cast<const float4*>(src);
  float4 b = *reinterpret_cast<const float4*>(src + 4);
  float v[8] = {a.x, a.y, a.z, a.w, b.x, b.y, b.z, b.w};
  half8 hi, lo;
#pragma unroll
  for (int j = 0; j < 8; ++j) {
    _Float16 h = (_Float16)v[j];
    hi[j] = h;
    lo[j] = (_Float16)(v[j] - (float)h);
  }
  size_t base = (((size_t)(ct * 64 + kc) * 2 + 0) * 64 + lane) * 8;
  *reinterpret_cast<half8*>(wf + base)       = hi;
  *reinterpret_cast<half8*>(wf + base + 512) = lo;
}

// LDS plan:
//   K-phase : xs[g][buf][split][32*LDA] halves = 20480 B @0
//   E-phase : Pacc 64x64 f32 @0 (16384) | Vb[32][66] @16384 | Eb[32][66] @24832
//             isum @33280 | ti @33408 | tp @33664  -> 33920 B total
__global__ __launch_bounds__(512, 4)
void gating_kernel(const float* __restrict__ x, const float* __restrict__ rn,
                   const _Float16* __restrict__ wf, const float* __restrict__ bg,
                   float* __restrict__ out,
                   float* __restrict__ cnt_g, float* __restrict__ psum_g) {
  __shared__ char smem[33920];
  _Float16* xs   = (_Float16*)smem;
  float*    Pacc = (float*)smem;
  float*    Vb   = (float*)(smem + 16384);
  float*    Eb   = (float*)(smem + 24832);
  float*    isum = (float*)(smem + 33280);
  int*      ti   = (int*)(smem + 33408);
  float*    tp   = (float*)(smem + 33664);

  const int t  = threadIdx.x;
  const int g  = t >> 8;        // K-group: 0 -> K[0,1024), 1 -> K[1024,2048)
  const int tg = t & 255;
  const int w4 = tg >> 6;       // ct-pair 0..3 -> expert cols [w4*16, +16)
  const int l  = t & 63;
  const int q  = l >> 4;
  const int cl = l & 15;
  const int c  = w4 * 16 + cl;
  const int t0 = blockIdx.x * MT;

  // x staging (per group): thread covers token tg>>3, k-offset (tg&7)*4
  const int stok = tg >> 3;
  const int skof = (tg & 7) * 4;
  const float* xrow = x + (size_t)(t0 + stok) * DD + g * (NKC * BK) + skof;

  // epilogue operands (group 0 only)
  float bgv = 0.f;
  float rnv[2][4] = {{0.f,0.f,0.f,0.f},{0.f,0.f,0.f,0.f}};
  if (g == 0) {
    bgv = bg[c];
#pragma unroll
    for (int mt = 0; mt < 2; ++mt)
#pragma unroll
      for (int r = 0; r < 4; ++r)
        rnv[mt][r] = rn[(size_t)(t0 + mt * 16 + q * 4 + r) * EE + c];
  }

  floatx4 acc[2][2];
#pragma unroll
  for (int mt = 0; mt < 2; ++mt)
#pragma unroll
    for (int nt = 0; nt < 2; ++nt) acc[mt][nt] = (floatx4)0.f;

  const half8* wfp = (const half8*)wf;
  half8 B[2][2][2];   // [parity][nt][s]

  // ---- preamble: chunk 0 of this group ----
  {
    float4 a = *reinterpret_cast<const float4*>(xrow);
    float v[4] = {a.x, a.y, a.z, a.w};
    half4v hi, lo;
#pragma unroll
    for (int j = 0; j < 4; ++j) {
      _Float16 h = (_Float16)v[j];
      hi[j] = h;
      lo[j] = (_Float16)(v[j] - (float)h);
    }
    *reinterpret_cast<half4v*>(&xs[((g * 2 + 0) * 2 + 0) * (MT * LDA) + stok * LDA + skof]) = hi;
    *reinterpret_cast<half4v*>(&xs[((g * 2 + 0) * 2 + 1) * (MT * LDA) + stok * LDA + skof]) = lo;
#pragma unroll
    for (int nt = 0; nt < 2; ++nt) {
      const int ct = w4 + nt * 4;
#pragma unroll
      for (int s = 0; s < 2; ++s)
        B[0][nt][s] = wfp[((size_t)(ct * 64 + g * NKC) * 2 + s) * 64 + l];
    }
  }

#pragma unroll 4
  for (int kc = 0; kc < NKC; ++kc) {
    const int cur = kc & 1;
    const bool more = (kc < NKC - 1);
    float4 pa;
    if (more) {
      pa = *reinterpret_cast<const float4*>(xrow + (kc + 1) * BK);
#pragma unroll
      for (int nt = 0; nt < 2; ++nt) {
        const int ct = w4 + nt * 4;
#pragma unroll
        for (int s = 0; s < 2; ++s)
          B[cur ^ 1][nt][s] = wfp[((size_t)(ct * 64 + g * NKC + kc + 1) * 2 + s) * 64 + l];
      }
    }
    // T4 counted-wait barrier: order LDS producer->consumer (lgkmcnt(0)) but
    // leave the pa / B prefetch loads IN FLIGHT across the barrier. The
    // compiler still inserts precise vmcnt waits before their uses. This
    // replaces __syncthreads(), whose vmcnt(0) drain serialized all loads
    // (measured: ~1 KB in flight per CU -> 740 GB/s).
    asm volatile("s_waitcnt lgkmcnt(0)" ::: "memory");
    __builtin_amdgcn_s_barrier();

    half8 Ah[2], Al[2];
#pragma unroll
    for (int mt = 0; mt < 2; ++mt) {
      Ah[mt] = *reinterpret_cast<const half8*>(
          &xs[((g * 2 + cur) * 2 + 0) * (MT * LDA) + (mt * 16 + cl) * LDA + q * 8]);
      Al[mt] = *reinterpret_cast<const half8*>(
          &xs[((g * 2 + cur) * 2 + 1) * (MT * LDA) + (mt * 16 + cl) * LDA + q * 8]);
    }
    // split-2 product: hi*hi + hi*lo + lo*hi  (12 MFMA)
#pragma unroll
    for (int mt = 0; mt < 2; ++mt)
#pragma unroll
      for (int nt = 0; nt < 2; ++nt)
        acc[mt][nt] = __builtin_amdgcn_mfma_f32_16x16x32_f16(Ah[mt], B[cur][nt][0], acc[mt][nt], 0, 0, 0);
#pragma unroll
    for (int mt = 0; mt < 2; ++mt)
#pragma unroll
      for (int nt = 0; nt < 2; ++nt)
        acc[mt][nt] = __builtin_amdgcn_mfma_f32_16x16x32_f16(Ah[mt], B[cur][nt][1], acc[mt][nt], 0, 0, 0);
#pragma unroll
    for (int mt = 0; mt < 2; ++mt)
#pragma unroll
      for (int nt = 0; nt < 2; ++nt)
        acc[mt][nt] = __builtin_amdgcn_mfma_f32_16x16x32_f16(Al[mt], B[cur][nt][0], acc[mt][nt], 0, 0, 0);

    if (more) {
      float v[4] = {pa.x, pa.y, pa.z, pa.w};
      half4v hi, lo;
#pragma unroll
      for (int j = 0; j < 4; ++j) {
        _Float16 h = (_Float16)v[j];
        hi[j] = h;
        lo[j] = (_Float16)(v[j] - (float)h);
      }
      *reinterpret_cast<half4v*>(&xs[((g * 2 + (cur ^ 1)) * 2 + 0) * (MT * LDA) + stok * LDA + skof]) = hi;
      *reinterpret_cast<half4v*>(&xs[((g * 2 + (cur ^ 1)) * 2 + 1) * (MT * LDA) + stok * LDA + skof]) = lo;
    }
  }

  __syncthreads();   // xs dead; smem becomes Pacc/Vb/Eb (full drain OK, once)

  // ---- split-K merge: group 1 -> LDS, group 0 adds ----
  if (g == 1) {
#pragma unroll
    for (int mt = 0; mt < 2; ++mt)
#pragma unroll
      for (int nt = 0; nt < 2; ++nt)
#pragma unroll
        for (int r = 0; r < 4; ++r)
          Pacc[((((w4 * 2 + mt) * 2 + nt) * 4) + r) * 64 + l] = acc[mt][nt][r];
  }
  __syncthreads();

  if (g == 0) {
#pragma unroll
    for (int mt = 0; mt < 2; ++mt)
#pragma unroll
      for (int nt = 0; nt < 2; ++nt)
#pragma unroll
        for (int r = 0; r < 4; ++r)
          acc[mt][nt][r] += Pacc[((((w4 * 2 + mt) * 2 + nt) * 4) + r) * 64 + l];

    // lane pass: noisy logit + exp, in-register (gate/noise same lane)
#pragma unroll
    for (int mt = 0; mt < 2; ++mt)
#pragma unroll
      for (int r = 0; r < 4; ++r) {
        const int tk = mt * 16 + q * 4 + r;   // C/D layout: row = q*4+r
        float gt = acc[mt][0][r] + bgv;
        float h  = acc[mt][1][r];
        float sp = (h > 20.f) ? h : log1pf(expf(h));
        float v  = gt + rnv[mt][r] * (sp + 0.01f);
        Vb[tk * 66 + c] = v;
        Eb[tk * 66 + c] = expf(v);
      }
  }
  __syncthreads();

  // ---- per-token top-2 + softmax denom (32 threads) ----
  if (t < MT) {
    float v1 = -1e30f, v2 = -1e30f;
    int   i1 = 0, i2 = 0;
    float s = 0.f;
    for (int e = 0; e < EE; ++e) {
      float v = Vb[t * 66 + e];
      s += Eb[t * 66 + e];
      if (v > v1)      { v2 = v1; i2 = i1; v1 = v; i1 = e; }
      else if (v > v2) { v2 = v;  i2 = e; }
    }
    isum[t] = 1.f / s;
    ti[t * 2 + 0] = i1; ti[t * 2 + 1] = i2;
    float e2 = expf(v2 - v1);
    float dn = 1.f + e2;
    tp[t * 2 + 0] = 1.f / dn;
    tp[t * 2 + 1] = e2 / dn;
  }
  __syncthreads();

  // ---- sparse out: patched zero-fill, all 512 threads, one float4 each ----
  {
    const int m  = t >> 4;
    const int c0 = (t & 15) * 4;
    const int i1 = ti[m * 2 + 0], i2 = ti[m * 2 + 1];
    const float p1 = tp[m * 2 + 0], p2 = tp[m * 2 + 1];
    float o[4];
#pragma unroll
    for (int j = 0; j < 4; ++j) {
      const int col = c0 + j;
      o[j] = (col == i1) ? p1 : ((col == i2) ? p2 : 0.f);
    }
    *reinterpret_cast<float4*>(out + (size_t)(t0 + m) * EE + c0) =
        make_float4(o[0], o[1], o[2], o[3]);
  }

  // ---- aux partials: per-expert psum & count ----
  if (t < EE) {
    float s = 0.f;
    int   cn = 0;
#pragma unroll
    for (int m = 0; m < MT; ++m) {
      s  += Eb[m * 66 + t] * isum[m];
      cn += (ti[m * 2 + 0] == t) + (ti[m * 2 + 1] == t);
    }
    atomicAdd(&psum_g[t], s);
    atomicAdd(&cnt_g[t], (float)cn);
  }
}

__global__ void aux_kernel(const float* __restrict__ cnt_g,
                           const float* __restrict__ psum_g,
                           float* __restrict__ out) {
  int e = threadIdx.x;  // 64 lanes, one wave
  float v = cnt_g[e] * psum_g[e];
#pragma unroll
  for (int o = 32; o > 0; o >>= 1) v += __shfl_down(v, o);
  if (e == 0)
    out[(size_t)TOK * EE] = v * ((float)EE / ((float)TOK * (float)TOK));
}

extern "C" void kernel_launch(void* const* d_in, const int* in_sizes, int n_in,
                              void* d_out, int out_size, void* d_ws, size_t ws_size,
                              hipStream_t stream) {
  const float* x  = (const float*)d_in[0];
  const float* rn = (const float*)d_in[1];
  const float* Wg = (const float*)d_in[2];
  const float* bg = (const float*)d_in[3];
  const float* Wn = (const float*)d_in[4];
  float* out    = (float*)d_out;
  float* cnt_g  = (float*)d_ws;
  float* psum_g = cnt_g + EE;
  _Float16* wf  = (_Float16*)((float*)d_ws + 128);   // 1 MiB of pre-split W frags

  hipMemsetAsync(d_ws, 0, 2 * EE * sizeof(float), stream);
  build_wf<<<128, 256, 0, stream>>>(Wg, Wn, wf);
  gating_kernel<<<TOK / MT, 512, 0, stream>>>(x, rn, wf, bg, out, cnt_g, psum_g);
  aux_kernel<<<1, 64, 0, stream>>>(cnt_g, psum_g, out);
}

// Round 7
// 226.888 us; speedup vs baseline: 1.1615x; 1.0467x over previous
//
#include <hip/hip_runtime.h>
#include <math.h>

#define TOK 16384
#define DD  2048
#define EE  64
#define MT  32           // tokens per block
#define BK  128          // k per chunk = 4 MFMA sub-steps of 32
#define NKC 8            // chunks per K-group (group covers 1024)
#define LDA 136          // halves per token row per split (272B stride, padded)
#define XREG (MT * LDA)  // halves per (g,buf,split) region

typedef _Float16 half4v __attribute__((ext_vector_type(4)));
typedef _Float16 half8  __attribute__((ext_vector_type(8)));
typedef float    floatx4 __attribute__((ext_vector_type(4)));

// ---- W pre-split: f32 -> (hi,lo) f16, frag-major layout ----
// wf frag index ((ct*64+kc)*2+s)*64+lane, 8 halves each (kc = 32-k chunk 0..63).
// ct 0..3 = gate col-tiles (cols ct*16+cl), ct 4..7 = noise col-tiles.
__global__ void build_wf(const float* __restrict__ Wg, const float* __restrict__ Wn,
                         _Float16* __restrict__ wf) {
  int tid  = blockIdx.x * 256 + threadIdx.x;   // 32768 threads
  int lane = tid & 63;
  int kc   = (tid >> 6) & 63;
  int ct   = tid >> 12;                        // 0..7
  int col  = (ct & 3) * 16 + (lane & 15);
  int k    = kc * 32 + (lane >> 4) * 8;
  const float* W = (ct < 4) ? Wg : Wn;
  const float* src = W + (size_t)col * DD + k;
  float4 a = *reinterpret_cast<const float4*>(src);
  float4 b = *reinterpret_cast<const float4*>(src + 4);
  float v[8] = {a.x, a.y, a.z, a.w, b.x, b.y, b.z, b.w};
  half8 hi, lo;
#pragma unroll
  for (int j = 0; j < 8; ++j) {
    _Float16 h = (_Float16)v[j];
    hi[j] = h;
    lo[j] = (_Float16)(v[j] - (float)h);
  }
  size_t base = (((size_t)(ct * 64 + kc) * 2 + 0) * 64 + lane) * 8;
  *reinterpret_cast<half8*>(wf + base)       = hi;
  *reinterpret_cast<half8*>(wf + base + 512) = lo;
}

// Convert+store one 128-float chunk row-slice (4x float4) into buffer BUF.
#define STAGE(BUF, P0, P1, P2, P3)                                              \
  {                                                                             \
    float4 pav[4] = {P0, P1, P2, P3};                                           \
    _Float16* xh = xs + ((g * 2 + (BUF)) * 2 + 0) * XREG + stok * LDA + skof;   \
    _Float16* xl = xh + XREG;                                                   \
    _Pragma("unroll")                                                           \
    for (int j = 0; j < 4; ++j) {                                               \
      float v[4] = {pav[j].x, pav[j].y, pav[j].z, pav[j].w};                    \
      half4v hi, lo;                                                            \
      _Pragma("unroll")                                                         \
      for (int jj = 0; jj < 4; ++jj) {                                          \
        _Float16 h = (_Float16)v[jj];                                           \
        hi[jj] = h;                                                             \
        lo[jj] = (_Float16)(v[jj] - (float)h);                                  \
      }                                                                         \
      *reinterpret_cast<half4v*>(xh + j * 32) = hi;                             \
      *reinterpret_cast<half4v*>(xl + j * 32) = lo;                             \
    }                                                                           \
  }

// One 32-k MFMA sub-step: consume B slot SC, prefetch next sub-step into SP.
// MFMA order (hi*hi, hi*lo, lo*hi) and k-order identical to the verified kernel.
#define SUBK(KK, SC, SP, DOPF)                                                  \
  {                                                                             \
    half8 Ah[2], Al[2];                                                         \
    _Pragma("unroll")                                                           \
    for (int mt = 0; mt < 2; ++mt) {                                            \
      Ah[mt] = *reinterpret_cast<const half8*>(xsh + (mt * 16) * LDA + (KK) * 32); \
      Al[mt] = *reinterpret_cast<const half8*>(xsl + (mt * 16) * LDA + (KK) * 32); \
    }                                                                           \
    if (DOPF) {                                                                 \
      const int ck = g * 32 + kc * 4 + (KK) + 1;                                \
      _Pragma("unroll")                                                         \
      for (int nt = 0; nt < 2; ++nt) {                                          \
        const int ct = w4 + nt * 4;                                             \
        _Pragma("unroll")                                                       \
        for (int s = 0; s < 2; ++s)                                             \
          SP[nt][s] = wfp[((size_t)(ct * 64 + ck) * 2 + s) * 64 + l];           \
      }                                                                         \
    }                                                                           \
    _Pragma("unroll")                                                           \
    for (int mt = 0; mt < 2; ++mt)                                              \
      _Pragma("unroll")                                                         \
      for (int nt = 0; nt < 2; ++nt)                                            \
        acc[mt][nt] = __builtin_amdgcn_mfma_f32_16x16x32_f16(Ah[mt], SC[nt][0], acc[mt][nt], 0, 0, 0); \
    _Pragma("unroll")                                                           \
    for (int mt = 0; mt < 2; ++mt)                                              \
      _Pragma("unroll")                                                         \
      for (int nt = 0; nt < 2; ++nt)                                            \
        acc[mt][nt] = __builtin_amdgcn_mfma_f32_16x16x32_f16(Ah[mt], SC[nt][1], acc[mt][nt], 0, 0, 0); \
    _Pragma("unroll")                                                           \
    for (int mt = 0; mt < 2; ++mt)                                              \
      _Pragma("unroll")                                                         \
      for (int nt = 0; nt < 2; ++nt)                                            \
        acc[mt][nt] = __builtin_amdgcn_mfma_f32_16x16x32_f16(Al[mt], SC[nt][0], acc[mt][nt], 0, 0, 0); \
  }

// LDS plan:
//   K-phase : xs[(g*2+buf)*2+split][32*LDA] halves = 8 regions x 8704 B = 69632 B
//   E-phase : overlay — Pacc 64x64 f32 @0 | Vb[32][66] @16384 | Eb[32][66] @24832
//             isum @33280 | ti @33408 | tp @33664  (33920 B < 69632)
__global__ __launch_bounds__(512, 4)
void gating_kernel(const float* __restrict__ x, const float* __restrict__ rn,
                   const _Float16* __restrict__ wf, const float* __restrict__ bg,
                   float* __restrict__ out,
                   float* __restrict__ cnt_g, float* __restrict__ psum_g) {
  __shared__ char smem[69632];
  _Float16* xs   = (_Float16*)smem;
  float*    Pacc = (float*)smem;
  float*    Vb   = (float*)(smem + 16384);
  float*    Eb   = (float*)(smem + 24832);
  float*    isum = (float*)(smem + 33280);
  int*      ti   = (int*)(smem + 33408);
  float*    tp   = (float*)(smem + 33664);

  const int t  = threadIdx.x;
  const int g  = t >> 8;        // K-group: 0 -> K[0,1024), 1 -> K[1024,2048)
  const int tg = t & 255;
  const int w4 = tg >> 6;       // ct-pair 0..3 -> expert cols [w4*16, +16)
  const int l  = t & 63;
  const int q  = l >> 4;
  const int cl = l & 15;
  const int c  = w4 * 16 + cl;
  const int t0 = blockIdx.x * MT;

  // x staging (per group): thread covers token tg>>3, float-offset (tg&7)*4
  const int stok = tg >> 3;
  const int skof = (tg & 7) * 4;
  const float* xrow = x + (size_t)(t0 + stok) * DD + g * (NKC * BK) + skof;

  // epilogue operands (group 0 only)
  float bgv = 0.f;
  float rnv[2][4] = {{0.f,0.f,0.f,0.f},{0.f,0.f,0.f,0.f}};
  if (g == 0) {
    bgv = bg[c];
#pragma unroll
    for (int mt = 0; mt < 2; ++mt)
#pragma unroll
      for (int r = 0; r < 4; ++r)
        rnv[mt][r] = rn[(size_t)(t0 + mt * 16 + q * 4 + r) * EE + c];
  }

  floatx4 acc[2][2];
#pragma unroll
  for (int mt = 0; mt < 2; ++mt)
#pragma unroll
    for (int nt = 0; nt < 2; ++nt) acc[mt][nt] = (floatx4)0.f;

  const half8* wfp = (const half8*)wf;
  half8 Bs0[2][2], Bs1[2][2];   // static 2-slot ring, distance-1 prefetch

  // ---- preamble: stage chunk 0 of this group; load B sub-step 0 ----
  {
    float4 a0 = *reinterpret_cast<const float4*>(xrow);
    float4 a1 = *reinterpret_cast<const float4*>(xrow + 32);
    float4 a2 = *reinterpret_cast<const float4*>(xrow + 64);
    float4 a3 = *reinterpret_cast<const float4*>(xrow + 96);
    STAGE(0, a0, a1, a2, a3)
    const int ck0 = g * 32;
#pragma unroll
    for (int nt = 0; nt < 2; ++nt) {
      const int ct = w4 + nt * 4;
#pragma unroll
      for (int s = 0; s < 2; ++s)
        Bs0[nt][s] = wfp[((size_t)(ct * 64 + ck0) * 2 + s) * 64 + l];
    }
  }

#pragma unroll 2
  for (int kc = 0; kc < NKC; ++kc) {
    const int cur = kc & 1;
    const bool more = (kc < NKC - 1);
    float4 p0, p1, p2, p3;
    if (more) {
      const float* xn = xrow + (kc + 1) * BK;
      p0 = *reinterpret_cast<const float4*>(xn);
      p1 = *reinterpret_cast<const float4*>(xn + 32);
      p2 = *reinterpret_cast<const float4*>(xn + 64);
      p3 = *reinterpret_cast<const float4*>(xn + 96);
    }
    // counted barrier: order LDS producer->consumer, leave global loads in flight
    asm volatile("s_waitcnt lgkmcnt(0)" ::: "memory");
    __builtin_amdgcn_s_barrier();

    const _Float16* xsh = xs + ((g * 2 + cur) * 2 + 0) * XREG + cl * LDA + q * 8;
    const _Float16* xsl = xsh + XREG;

    SUBK(0, Bs0, Bs1, 1)
    SUBK(1, Bs1, Bs0, 1)
    SUBK(2, Bs0, Bs1, 1)
    SUBK(3, Bs1, Bs0, more)   // prefetches next chunk's sub-step 0 into Bs0

    if (more) {
      STAGE(cur ^ 1, p0, p1, p2, p3)
    }
  }

  __syncthreads();   // xs dead; smem becomes Pacc/Vb/Eb (full drain OK, once)

  // ---- split-K merge: group 1 -> LDS, group 0 adds ----
  if (g == 1) {
#pragma unroll
    for (int mt = 0; mt < 2; ++mt)
#pragma unroll
      for (int nt = 0; nt < 2; ++nt)
#pragma unroll
        for (int r = 0; r < 4; ++r)
          Pacc[((((w4 * 2 + mt) * 2 + nt) * 4) + r) * 64 + l] = acc[mt][nt][r];
  }
  __syncthreads();

  if (g == 0) {
#pragma unroll
    for (int mt = 0; mt < 2; ++mt)
#pragma unroll
      for (int nt = 0; nt < 2; ++nt)
#pragma unroll
        for (int r = 0; r < 4; ++r)
          acc[mt][nt][r] += Pacc[((((w4 * 2 + mt) * 2 + nt) * 4) + r) * 64 + l];

    // lane pass: noisy logit + exp, in-register (gate/noise same lane)
#pragma unroll
    for (int mt = 0; mt < 2; ++mt)
#pragma unroll
      for (int r = 0; r < 4; ++r) {
        const int tk = mt * 16 + q * 4 + r;   // C/D layout: row = q*4+r
        float gt = acc[mt][0][r] + bgv;
        float h  = acc[mt][1][r];
        float sp = (h > 20.f) ? h : log1pf(expf(h));
        float v  = gt + rnv[mt][r] * (sp + 0.01f);
        Vb[tk * 66 + c] = v;
        Eb[tk * 66 + c] = expf(v);
      }
  }
  __syncthreads();

  // ---- per-token top-2 + softmax denom (32 threads) ----
  if (t < MT) {
    float v1 = -1e30f, v2 = -1e30f;
    int   i1 = 0, i2 = 0;
    float s = 0.f;
    for (int e = 0; e < EE; ++e) {
      float v = Vb[t * 66 + e];
      s += Eb[t * 66 + e];
      if (v > v1)      { v2 = v1; i2 = i1; v1 = v; i1 = e; }
      else if (v > v2) { v2 = v;  i2 = e; }
    }
    isum[t] = 1.f / s;
    ti[t * 2 + 0] = i1; ti[t * 2 + 1] = i2;
    float e2 = expf(v2 - v1);
    float dn = 1.f + e2;
    tp[t * 2 + 0] = 1.f / dn;
    tp[t * 2 + 1] = e2 / dn;
  }
  __syncthreads();

  // ---- sparse out: patched zero-fill, all 512 threads, one float4 each ----
  {
    const int m  = t >> 4;
    const int c0 = (t & 15) * 4;
    const int i1 = ti[m * 2 + 0], i2 = ti[m * 2 + 1];
    const float p1 = tp[m * 2 + 0], p2 = tp[m * 2 + 1];
    float o[4];
#pragma unroll
    for (int j = 0; j < 4; ++j) {
      const int col = c0 + j;
      o[j] = (col == i1) ? p1 : ((col == i2) ? p2 : 0.f);
    }
    *reinterpret_cast<float4*>(out + (size_t)(t0 + m) * EE + c0) =
        make_float4(o[0], o[1], o[2], o[3]);
  }

  // ---- aux partials: per-expert psum & count ----
  if (t < EE) {
    float s = 0.f;
    int   cn = 0;
#pragma unroll
    for (int m = 0; m < MT; ++m) {
      s  += Eb[m * 66 + t] * isum[m];
      cn += (ti[m * 2 + 0] == t) + (ti[m * 2 + 1] == t);
    }
    atomicAdd(&psum_g[t], s);
    atomicAdd(&cnt_g[t], (float)cn);
  }
}

__global__ void aux_kernel(const float* __restrict__ cnt_g,
                           const float* __restrict__ psum_g,
                           float* __restrict__ out) {
  int e = threadIdx.x;  // 64 lanes, one wave
  float v = cnt_g[e] * psum_g[e];
#pragma unroll
  for (int o = 32; o > 0; o >>= 1) v += __shfl_down(v, o);
  if (e == 0)
    out[(size_t)TOK * EE] = v * ((float)EE / ((float)TOK * (float)TOK));
}

extern "C" void kernel_launch(void* const* d_in, const int* in_sizes, int n_in,
                              void* d_out, int out_size, void* d_ws, size_t ws_size,
                              hipStream_t stream) {
  const float* x  = (const float*)d_in[0];
  const float* rn = (const float*)d_in[1];
  const float* Wg = (const float*)d_in[2];
  const float* bg = (const float*)d_in[3];
  const float* Wn = (const float*)d_in[4];
  float* out    = (float*)d_out;
  float* cnt_g  = (float*)d_ws;
  float* psum_g = cnt_g + EE;
  _Float16* wf  = (_Float16*)((float*)d_ws + 128);   // 1 MiB of pre-split W frags

  hipMemsetAsync(d_ws, 0, 2 * EE * sizeof(float), stream);
  build_wf<<<128, 256, 0, stream>>>(Wg, Wn, wf);
  gating_kernel<<<TOK / MT, 512, 0, stream>>>(x, rn, wf, bg, out, cnt_g, psum_g);
  aux_kernel<<<1, 64, 0, stream>>>(cnt_g, psum_g, out);
}